// Round 12
// baseline (700.697 us; speedup 1.0000x reference)
//
#include <hip/hip_runtime.h>
#include <hip/hip_bf16.h>

// CustomLMHead: C[M,N] = X[M,K] @ (Wq[N,K] * scale[N])^T
// M=2048, N=151936, K=896.
//
// INT8 path: W exactly int8; X quantized per-row (absmax/127, RNE);
// C = (Xq . Wq8) * Sx[m] * Sw[n], exact int32 accumulation via
// mfma_i32_16x16x64_i8. 128x128 tile, 4 waves (64x64/wave), triple-buffered
// 48 KiB LDS, 3 blocks/CU, T2 swizzle, coalesced LDS epilogue (rounds 9/10,
// proven). THIS ROUND: in-wave software pipeline — per body t:
//   vmcnt(4); lgkmcnt(0); barrier;            // publishes tile t+1
//   READ frags(t+1) -> other reg set  ||  stage(t+3)  ||  16 MFMA on frags(t)
// so LDS reads overlap MFMA instead of alternating in barrier-locked phases.
//   RAW: stage(t+1) issued body t-2; vmcnt(4) at body t retires it; barrier
//        publishes; frags(t+1) read after that barrier.
//   WAR: buf[t%3] overwritten by stage(t+3) (issued after barrier(t));
//        frags(t) reads (body t-1) drained by lgkmcnt(0) before barrier(t).
// Fully unrolled (14 bodies) so fragment sets are statically named.
// Fallback (small ws): bf16 reg-staging kernel with in-loop conversion.

#define M_DIM 2048
#define N_DIM 151936
#define K_DIM 896

#define BM 128
#define BN 128
#define BK 64                   // int8 K per tile (64 bytes/row slice)
#define NKT (K_DIM / BK)        // 14
#define MB_CNT (M_DIM / BM)     // 16
#define NB_CNT (N_DIM / BN)     // 1187 (exact)
#define NWG (MB_CNT * NB_CNT)   // 18992, divisible by 8

typedef __attribute__((ext_vector_type(8))) short bf16x8;
typedef __attribute__((ext_vector_type(4))) float f32x4;
typedef __attribute__((ext_vector_type(4))) int   i32x4;
typedef __attribute__((ext_vector_type(4))) unsigned int u32x4;
typedef __attribute__((ext_vector_type(2))) unsigned int u32x2;

static __device__ __forceinline__ unsigned short f2bf(float f) {
    unsigned int u = __builtin_bit_cast(unsigned int, f);
    u += 0x7FFFu + ((u >> 16) & 1u);
    return (unsigned short)(u >> 16);
}
static __device__ __forceinline__ unsigned int pack2(float lo, float hi) {
    return (unsigned int)f2bf(lo) | ((unsigned int)f2bf(hi) << 16);
}
static __device__ __forceinline__ void gload_lds16(const void* g, void* l) {
    __builtin_amdgcn_global_load_lds(
        (const __attribute__((address_space(1))) unsigned int*)g,
        (__attribute__((address_space(3))) unsigned int*)l, 16, 0, 0);
}

// ---------------- preconvert kernels (proven rounds 9-11) ----------------

__global__ void quant_x_kernel(const float* __restrict__ X,
                               signed char* __restrict__ Xq,
                               float* __restrict__ Sx) {
    const int row  = blockIdx.x * 4 + (threadIdx.x >> 6);
    const int lane = threadIdx.x & 63;
    const float* xr = X + (size_t)row * K_DIM;
    float v[14];
    float am = 0.f;
    #pragma unroll
    for (int i = 0; i < 14; ++i) {
        v[i] = xr[lane + i * 64];
        am = fmaxf(am, fabsf(v[i]));
    }
    #pragma unroll
    for (int off = 32; off > 0; off >>= 1)
        am = fmaxf(am, __shfl_xor(am, off));
    am = fmaxf(am, 1e-20f);
    const float inv = 127.f / am;
    if (lane == 0) Sx[row] = am / 127.f;
    signed char* qr = Xq + (size_t)row * K_DIM;
    #pragma unroll
    for (int i = 0; i < 14; ++i)
        qr[lane + i * 64] = (signed char)(int)rintf(v[i] * inv);
}

__global__ void cvt_w8_kernel(const int* __restrict__ Wq,
                              signed char* __restrict__ W8) {
    const long n8 = (long)N_DIM * K_DIM / 8;
    for (long i = (long)blockIdx.x * blockDim.x + threadIdx.x; i < n8;
         i += (long)gridDim.x * blockDim.x) {
        i32x4 a = ((const i32x4*)Wq)[2 * i];
        i32x4 b = ((const i32x4*)Wq)[2 * i + 1];
        unsigned int lo = (unsigned int)(a[0] & 0xff) |
                          ((unsigned int)(a[1] & 0xff) << 8) |
                          ((unsigned int)(a[2] & 0xff) << 16) |
                          ((unsigned int)(a[3] & 0xff) << 24);
        unsigned int hi = (unsigned int)(b[0] & 0xff) |
                          ((unsigned int)(b[1] & 0xff) << 8) |
                          ((unsigned int)(b[2] & 0xff) << 16) |
                          ((unsigned int)(b[3] & 0xff) << 24);
        u32x2 o; o[0] = lo; o[1] = hi;
        ((u32x2*)W8)[i] = o;
    }
}

// ---------------- 128x128 pipelined INT8 GEMM ----------------

#define SCHED0 __builtin_amdgcn_sched_barrier(0)
#define VMCNT(N) asm volatile("s_waitcnt vmcnt(" #N ")" ::: "memory")
#define LGKM0    asm volatile("s_waitcnt lgkmcnt(0)" ::: "memory")

__global__ __launch_bounds__(256, 3)
void lmhead_gemm_i8(const signed char* __restrict__ Xq,
                    const signed char* __restrict__ W8,
                    const float* __restrict__ Sw,
                    const float* __restrict__ Sx,
                    float* __restrict__ O)
{
    // [buf3][mat A=0/B=1][row 128][col 64 i8] = 48 KiB
    __shared__ signed char lds[3][2][BM][BK];

    const int tid  = threadIdx.x;
    const int lane = tid & 63;
    const int wave = tid >> 6;      // 0..3
    const int wr   = wave >> 1;     // 0..1
    const int wc   = wave & 1;      // 0..1

    // XCD-chunked bijective swizzle; mb fastest so the 16 m-blocks sharing
    // one 128-row W strip co-locate on one XCD's L2.
    const int bid = blockIdx.x;
    const int wg  = (bid & 7) * (NWG / 8) + (bid >> 3);
    const int mb  = wg % MB_CNT;
    const int nb  = wg / MB_CNT;

    // staging: per gload_lds, wave covers 16 rows of 64B; dest row =
    // base + (lane>>2), phys 16B-slot = lane&3. T2 swizzle phys =
    // logical ^ ((row>>1)&3) -> source slot = (lane&3) ^ ((lane>>3)&3).
    const int lslot = (lane & 3) ^ ((lane >> 3) & 3);
    const signed char* srcA0 =
        Xq + (size_t)(mb * BM + wave * 16 + (lane >> 2)) * K_DIM + lslot * 16;
    const signed char* srcA1 = srcA0 + (size_t)64 * K_DIM;
    const signed char* srcB0 =
        W8 + (size_t)(nb * BN + wave * 16 + (lane >> 2)) * K_DIM + lslot * 16;
    const signed char* srcB1 = srcB0 + (size_t)64 * K_DIM;

    auto stage = [&](int b3, int k0) {   // k0 in BYTES along K
        gload_lds16(srcA0 + k0, &lds[b3][0][wave * 16][0]);
        gload_lds16(srcA1 + k0, &lds[b3][0][64 + wave * 16][0]);
        gload_lds16(srcB0 + k0, &lds[b3][1][wave * 16][0]);
        gload_lds16(srcB1 + k0, &lds[b3][1][64 + wave * 16][0]);
    };

    // frag reads: row = R0 + (lane&15); lane holds 16 consecutive i8
    // (K-group = lane>>4); phys 16B-octet = (lane>>4) ^ ((lane>>1)&3).
    const int physoff   = ((lane >> 4) ^ ((lane >> 1) & 3)) * 16;   // bytes
    const int arow_base = wr * 64 + (lane & 15);
    const int brow_base = wc * 64 + (lane & 15);

    i32x4 acc[4][4];
    #pragma unroll
    for (int i = 0; i < 4; ++i)
        #pragma unroll
        for (int j = 0; j < 4; ++j)
            acc[i][j] = i32x4{0, 0, 0, 0};

    i32x4 afE[4], bfE[4], afO[4], bfO[4];   // even/odd fragment sets

#define READ_FRAGS(B3, AF, BF) do { \
    _Pragma("unroll") \
    for (int mf = 0; mf < 4; ++mf) \
        AF[mf] = *(const i32x4*)&lds[B3][0][arow_base + mf * 16][physoff]; \
    _Pragma("unroll") \
    for (int nf = 0; nf < 4; ++nf) \
        BF[nf] = *(const i32x4*)&lds[B3][1][brow_base + nf * 16][physoff]; \
} while (0)
#define MFMA16(AF, BF) do { \
    __builtin_amdgcn_s_setprio(1); \
    _Pragma("unroll") \
    for (int mf = 0; mf < 4; ++mf) { \
        _Pragma("unroll") \
        for (int nf = 0; nf < 4; ++nf) \
            acc[mf][nf] = __builtin_amdgcn_mfma_i32_16x16x64_i8( \
                AF[mf], BF[nf], acc[mf][nf], 0, 0, 0); \
    } \
    __builtin_amdgcn_s_setprio(0); \
} while (0)
// body T: sync; read frags(T+1); stage(T+3); MFMA(T). No fences between
// reads/stage/MFMA -> scheduler interleaves them (the overlap we want).
#define BODYF(T, AC, BC, AN, BN_) do { \
    SCHED0; VMCNT(4); LGKM0; SCHED0; \
    __builtin_amdgcn_s_barrier(); \
    SCHED0; \
    READ_FRAGS(((T) + 1) % 3, AN, BN_); \
    stage(((T) + 3) % 3, ((T) + 3) * BK); \
    MFMA16(AC, BC); \
} while (0)
#define BODYN(T, AC, BC, AN, BN_) do { \
    SCHED0; VMCNT(4); LGKM0; SCHED0; \
    __builtin_amdgcn_s_barrier(); \
    SCHED0; \
    READ_FRAGS(((T) + 1) % 3, AN, BN_); \
    MFMA16(AC, BC); \
} while (0)

    // prologue: stage tiles 0,1; retire tile 0; publish; preload frags(0)
    stage(0, 0);
    stage(1, BK);
    SCHED0; VMCNT(4); SCHED0;
    __builtin_amdgcn_s_barrier();
    SCHED0;
    READ_FRAGS(0, afE, bfE);
    stage(2, 2 * BK);

    // bodies 0..10 stage (t+3 <= 13); body 11 does not
    BODYF(0,  afE, bfE, afO, bfO);
    BODYF(1,  afO, bfO, afE, bfE);
    BODYF(2,  afE, bfE, afO, bfO);
    BODYF(3,  afO, bfO, afE, bfE);
    BODYF(4,  afE, bfE, afO, bfO);
    BODYF(5,  afO, bfO, afE, bfE);
    BODYF(6,  afE, bfE, afO, bfO);
    BODYF(7,  afO, bfO, afE, bfE);
    BODYF(8,  afE, bfE, afO, bfO);
    BODYF(9,  afO, bfO, afE, bfE);
    BODYF(10, afE, bfE, afO, bfO);
    BODYN(11, afO, bfO, afE, bfE);
    // body 12: only stage(13) outstanding -> vmcnt(0); reads frags(13)
    {
        SCHED0; VMCNT(0); LGKM0; SCHED0;
        __builtin_amdgcn_s_barrier();
        SCHED0;
        READ_FRAGS(13 % 3, afO, bfO);
        MFMA16(afE, bfE);
    }
    // body 13: frags already in regs; drain own reads, compute
    {
        SCHED0; LGKM0; SCHED0;
        MFMA16(afO, bfO);
    }

#undef READ_FRAGS
#undef MFMA16
#undef BODYF
#undef BODYN

    // ---- LDS-coalesced epilogue (proven rounds 9/10) ----
    // Reuse LDS as float[64][128] (32 KiB), 2 passes (row halves).
    // Writes: (float)acc * Sw[n], XOR-swizzled pcol = col ^ (qw<<4).
    // Reads: f32x4 * Sx[row] -> full 128B-line global row stores.
    __syncthreads();   // all K-loop work fully drained

    float* lf = (float*)&lds[0][0][0][0];
    const int qw = lane >> 4;     // 0..3
    const int li = lane & 15;

    float scn[4];
    #pragma unroll
    for (int nf = 0; nf < 4; ++nf)
        scn[nf] = Sw[nb * BN + wc * 64 + nf * 16 + li];

    #pragma unroll
    for (int p = 0; p < 2; ++p) {
        if (p) __syncthreads();   // pass-0 reads before pass-1 writes
        if (wr == p) {
            #pragma unroll
            for (int a = 0; a < 4; ++a) {
                #pragma unroll
                for (int nf = 0; nf < 4; ++nf) {
                    #pragma unroll
                    for (int r = 0; r < 4; ++r) {
                        const int lr   = a * 16 + qw * 4 + r;
                        const int col  = wc * 64 + nf * 16 + li;
                        const int pcol = col ^ (qw << 4);
                        lf[lr * 128 + pcol] = (float)acc[a][nf][r] * scn[nf];
                    }
                }
            }
        }
        __syncthreads();
        #pragma unroll
        for (int i = 0; i < 8; ++i) {
            const int row = wave * 16 + i * 2 + (lane >> 5);
            const int q   = (row >> 2) & 3;
            const int pch = (lane & 31) ^ (q << 2);
            f32x4 v = *(const f32x4*)&lf[row * 128 + pch * 4];
            const size_t grow = (size_t)(mb * BM + p * 64 + row);
            const float sxr = Sx[grow];
            v *= sxr;
            const size_t gcol = (size_t)(nb * BN + (lane & 31) * 4);
            *(f32x4*)&O[grow * N_DIM + gcol] = v;
        }
    }
}

// ---------------- fallback: bf16 reg staging + in-loop convert ----------------

#define FBM 128
#define FBN 128
#define FBK 32
#define FNSTEPS (K_DIM / FBK)
#define FMB (M_DIM / FBM)
#define FNB (N_DIM / FBN)
#define FNWG (FMB * FNB)

__global__ __launch_bounds__(256, 2)
void lmhead_gemm_conv(const float* __restrict__ X,
                      const int* __restrict__ Wq,
                      const float* __restrict__ S,
                      float* __restrict__ O)
{
    __shared__ unsigned short Alds[2][FBM][FBK];
    __shared__ unsigned short Blds2[2][FBN][FBK];

    const int tid  = threadIdx.x;
    const int lane = tid & 63;
    const int wave = tid >> 6;
    const int wr   = wave >> 1;
    const int wc   = wave & 1;

    const int bid = blockIdx.x;
    const int wg  = (bid & 7) * (FNWG / 8) + (bid >> 3);
    const int mb  = wg % FMB;
    const int nb  = wg / FMB;

    const int srow = tid >> 1;
    const int skh  = (tid & 1) * 16;

    const float* aptr = X  + (size_t)(mb * FBM + srow) * K_DIM + skh;
    const int*   wptr = Wq + (size_t)(nb * FBN + srow) * K_DIM + skh;

    f32x4 av[4];
    i32x4 wv[4];

    auto load_tiles = [&](int k0) {
        const f32x4* ap = (const f32x4*)(aptr + k0);
        const i32x4* wp = (const i32x4*)(wptr + k0);
        av[0] = ap[0]; av[1] = ap[1]; av[2] = ap[2]; av[3] = ap[3];
        wv[0] = wp[0]; wv[1] = wp[1]; wv[2] = wp[2]; wv[3] = wp[3];
    };

    auto stage = [&](int buf) {
        unsigned int apk[8], wpk[8];
        #pragma unroll
        for (int i = 0; i < 8; ++i) {
            apk[i] = pack2(av[(2*i) >> 2][(2*i) & 3], av[(2*i+1) >> 2][(2*i+1) & 3]);
            wpk[i] = pack2((float)wv[(2*i) >> 2][(2*i) & 3], (float)wv[(2*i+1) >> 2][(2*i+1) & 3]);
        }
        *(u32x4*)&Alds[buf][srow][skh]      = u32x4{apk[0], apk[1], apk[2], apk[3]};
        *(u32x4*)&Alds[buf][srow][skh + 8]  = u32x4{apk[4], apk[5], apk[6], apk[7]};
        *(u32x4*)&Blds2[buf][srow][skh]     = u32x4{wpk[0], wpk[1], wpk[2], wpk[3]};
        *(u32x4*)&Blds2[buf][srow][skh + 8] = u32x4{wpk[4], wpk[5], wpk[6], wpk[7]};
    };

    f32x4 acc[4][4];
    #pragma unroll
    for (int i = 0; i < 4; ++i)
        #pragma unroll
        for (int j = 0; j < 4; ++j)
            acc[i][j] = f32x4{0.f, 0.f, 0.f, 0.f};

    load_tiles(0);
    stage(0);
    __syncthreads();

    int cur = 0;
    for (int s = 0; s < FNSTEPS; ++s) {
        if (s + 1 < FNSTEPS) load_tiles((s + 1) * FBK);

        bf16x8 af[4], bfr[4];
        const int arow = wr * 64 + (lane & 15);
        const int brow = wc * 64 + (lane & 15);
        const int kb   = (lane >> 4) * 8;
        #pragma unroll
        for (int mf = 0; mf < 4; ++mf)
            af[mf] = *(const bf16x8*)&Alds[cur][arow + mf * 16][kb];
        #pragma unroll
        for (int nf = 0; nf < 4; ++nf)
            bfr[nf] = *(const bf16x8*)&Blds2[cur][brow + nf * 16][kb];

        #pragma unroll
        for (int mf = 0; mf < 4; ++mf)
            #pragma unroll
            for (int nf = 0; nf < 4; ++nf)
                acc[mf][nf] = __builtin_amdgcn_mfma_f32_16x16x32_bf16(
                    af[mf], bfr[nf], acc[mf][nf], 0, 0, 0);

        if (s + 1 < FNSTEPS) stage(cur ^ 1);
        __syncthreads();
        cur ^= 1;
    }

    #pragma unroll
    for (int nf = 0; nf < 4; ++nf) {
        const int n = nb * FBN + wc * 64 + nf * 16 + (lane & 15);
        const float sc = S[n];
        #pragma unroll
        for (int mf = 0; mf < 4; ++mf) {
            const int m0 = mb * FBM + wr * 64 + mf * 16 + ((lane >> 4) << 2);
            #pragma unroll
            for (int r = 0; r < 4; ++r)
                O[(size_t)(m0 + r) * N_DIM + n] = acc[mf][nf][r] * sc;
        }
    }
}

// ---------------- launch ----------------

extern "C" void kernel_launch(void* const* d_in, const int* in_sizes, int n_in,
                              void* d_out, int out_size, void* d_ws, size_t ws_size,
                              hipStream_t stream) {
    const float* X  = (const float*)d_in[0];
    const int*   Wq = (const int*)d_in[1];
    const float* S  = (const float*)d_in[2];
    float*       O  = (float*)d_out;

    const size_t XQ_BYTES = (size_t)M_DIM * K_DIM;            // 1,835,008
    const size_t SX_BYTES = (size_t)M_DIM * sizeof(float);    // 8,192
    const size_t W8_BYTES = (size_t)N_DIM * K_DIM;            // 136,134,656

    if (ws_size >= XQ_BYTES + SX_BYTES + W8_BYTES) {
        signed char* xq = (signed char*)d_ws;
        float*       sx = (float*)((char*)d_ws + XQ_BYTES);
        signed char* w8 = (signed char*)((char*)d_ws + XQ_BYTES + SX_BYTES);
        quant_x_kernel<<<M_DIM / 4, 256, 0, stream>>>(X, xq, sx);
        cvt_w8_kernel<<<2048, 256, 0, stream>>>(Wq, w8);
        lmhead_gemm_i8<<<NWG, 256, 0, stream>>>(xq, w8, S, sx, O);
    } else {
        lmhead_gemm_conv<<<FNWG, 256, 0, stream>>>(X, Wq, S, O);
    }
}